// Round 1
// baseline (186.065 us; speedup 1.0000x reference)
//
#include <hip/hip_runtime.h>
#include <hip/hip_bf16.h>
#include <cmath>

#define N_TOK 90000
#define DM 128
#define NH 8
#define DH 16
#define NS 1000
#define LS 90
#define LSP 96
#define DFF 256
#define VN 45000
#define NB_L 704   // ceil(VN/64)
#define NB_I 704   // ceil((N_TOK-VN)/64)

typedef __attribute__((ext_vector_type(8))) short short8;
typedef __attribute__((ext_vector_type(4))) short short4_t;
typedef __attribute__((ext_vector_type(4))) float f32x4;

#define SWZ(row, byte) ((byte) ^ (((row) & 7) << 4))

__device__ __forceinline__ unsigned short f2bf(float f) {
  __hip_bfloat16 h = __float2bfloat16(f);
  union { __hip_bfloat16 h; unsigned short u; } c; c.h = h; return c.u;
}
__device__ __forceinline__ float bf2f(unsigned short u) {
  union { unsigned short u; __hip_bfloat16 h; } c; c.u = u; return __bfloat162float(c.h);
}

// ---------------- K0: weights fp32 -> bf16, FRAGMENT-LINEAR layout ----------------
__global__ __launch_bounds__(256) void k_wconv(
    const float* __restrict__ a0, const float* __restrict__ a1,
    const float* __restrict__ a2, const float* __restrict__ a3,
    const float* __restrict__ a4, const float* __restrict__ a5,
    unsigned short* __restrict__ dst)
{
  int c = blockIdx.x * 256 + threadIdx.x;   // 96 blocks * 256 = 24576 chunks
  const float* s; int base, kkn, K;
  if      (c <  6144) { s = a0; base = 0;     kkn = 4; K = 128; }  // Wqkv 384x128
  else if (c <  8192) { s = a1; base = 6144;  kkn = 4; K = 128; }  // Wo   128x128
  else if (c < 12288) { s = a2; base = 8192;  kkn = 4; K = 128; }  // W1l  256x128
  else if (c < 16384) { s = a3; base = 12288; kkn = 4; K = 128; }  // W1i  256x128
  else if (c < 20480) { s = a4; base = 16384; kkn = 8; K = 256; }  // W2l  128x256
  else                { s = a5; base = 20480; kkn = 8; K = 256; }  // W2i  128x256
  int lc = c - base;
  int nt = lc / (kkn * 64);
  int rem = lc - nt * (kkn * 64);
  int kk = rem >> 6, l = rem & 63;
  int row = nt * 16 + (l & 15);
  int col = kk * 32 + (l >> 4) * 8;
  const float* sp = s + (size_t)row * K + col;
  short8 o;
  #pragma unroll
  for (int e = 0; e < 8; e++) o[e] = (short)f2bf(sp[e]);
  *(short8*)&dst[(size_t)c * 8] = o;
}

// ---------------- K1: per-set megakernel, phase-reordered for 3 blocks/CU ----------------
// grid NS x 512 (8 waves). LDS lifetime trick: K,V^T computed first; aV pulled to
// registers by all waves; then Q is computed INTO the V^T region (union). This cuts
// LDS 75776 -> ~50944 so 3 blocks/CU fit (was 2).
__global__ __launch_bounds__(512, 6) void k_set(
    const float* __restrict__ src, const float* __restrict__ pos,
    const int* __restrict__ inds, const unsigned char* __restrict__ masks,
    const unsigned short* __restrict__ Wq, const float* __restrict__ bq_,
    const unsigned short* __restrict__ Wo, const float* __restrict__ bo,
    const float* __restrict__ lg, const float* __restrict__ lb,
    const float* __restrict__ ig, const float* __restrict__ ib,
    unsigned short* __restrict__ x1)
{
  // K [96][256B bf16 swizzled] | union{ V^T [128][200B] ; Q/O [96][256B swizzled] }
  __shared__ __align__(16) char QKV[LSP * 256 + 128 * 200];
  __shared__ float bias[LSP];
  __shared__ int tok[LSP];
  const int s = blockIdx.x;
  const int tid = threadIdx.x;
  const int w = tid >> 6, l = tid & 63;
  const int g = l >> 4, cb = l & 15;

  if (tid < LSP) {
    tok[tid] = inds[s * LS + ((tid < LS) ? tid : 0)];
    bias[tid] = (tid < LS && !masks[s * LS + tid]) ? 0.f : -1e9f;
  }
  __syncthreads();

  char* Kd = QKV;
  char* Vt = QKV + LSP * 256;   // V^T: row=channel (128), col=key, 200B rows
  char* Qd = QKV + LSP * 256;   // aliases Vt — written only after aV consumed

  const int row = w * 16 + cb;
  short8 bq[4];                 // gathered q = sf+sp, lives through A1 and A2

  // ---- phase A1: gather + K,V projection -> LDS (waves 0..5), 2-stage W prefetch
  if (w < 6) {
    const int t = tok[row];
    short8 bv[4];
    #pragma unroll
    for (int kk = 0; kk < 4; kk++) {
      const float* sp = &src[(size_t)t * DM + kk * 32 + g * 8];
      const float* pp = &pos[(size_t)t * DM + kk * 32 + g * 8];
      float4 s0 = *(const float4*)sp, s1 = *(const float4*)(sp + 4);
      float4 p0 = *(const float4*)pp, p1 = *(const float4*)(pp + 4);
      short8 q, v;
      q[0] = (short)f2bf(s0.x + p0.x); q[1] = (short)f2bf(s0.y + p0.y);
      q[2] = (short)f2bf(s0.z + p0.z); q[3] = (short)f2bf(s0.w + p0.w);
      q[4] = (short)f2bf(s1.x + p1.x); q[5] = (short)f2bf(s1.y + p1.y);
      q[6] = (short)f2bf(s1.z + p1.z); q[7] = (short)f2bf(s1.w + p1.w);
      v[0] = (short)f2bf(s0.x); v[1] = (short)f2bf(s0.y);
      v[2] = (short)f2bf(s0.z); v[3] = (short)f2bf(s0.w);
      v[4] = (short)f2bf(s1.x); v[5] = (short)f2bf(s1.y);
      v[6] = (short)f2bf(s1.z); v[7] = (short)f2bf(s1.w);
      bq[kk] = q; bv[kk] = v;
    }

    short8 A0[4];
    {
      const unsigned short* wb = Wq + ((size_t)8 * 256 + l) * 8;
      #pragma unroll
      for (int kk = 0; kk < 4; kk++) A0[kk] = *(const short8*)(wb + kk * 512);
    }
    #pragma unroll
    for (int nt = 8; nt < 24; nt++) {
      short8 An[4];
      if (nt < 23) {
        const unsigned short* wb = Wq + ((size_t)(nt + 1) * 256 + l) * 8;
        #pragma unroll
        for (int kk = 0; kk < 4; kk++) An[kk] = *(const short8*)(wb + kk * 512);
      }
      f32x4 acc = {0.f, 0.f, 0.f, 0.f};
      if (nt < 16) {
        #pragma unroll
        for (int kk = 0; kk < 4; kk++)
          acc = __builtin_amdgcn_mfma_f32_16x16x32_bf16(A0[kk], bq[kk], acc, 0, 0, 0);
      } else {
        #pragma unroll
        for (int kk = 0; kk < 4; kk++)
          acc = __builtin_amdgcn_mfma_f32_16x16x32_bf16(A0[kk], bv[kk], acc, 0, 0, 0);
      }
      float4 bb = *(const float4*)&bq_[nt * 16 + g * 4];
      if (nt < 16) {
        const int colb = (nt & 7) * 16 + g * 4;
        short4_t o;
        o[0] = (short)f2bf(acc[0] + bb.x); o[1] = (short)f2bf(acc[1] + bb.y);
        o[2] = (short)f2bf(acc[2] + bb.z); o[3] = (short)f2bf(acc[3] + bb.w);
        *(short4_t*)(Kd + SWZ(row, row * 256 + colb * 2)) = o;
      } else {
        float bba[4] = {bb.x, bb.y, bb.z, bb.w};
        #pragma unroll
        for (int j = 0; j < 4; j++) {
          int ch = (nt - 16) * 16 + g * 4 + j;   // channel 0..127
          *(unsigned short*)(Vt + ch * 200 + row * 2) = f2bf(acc[j] + bba[j]);
        }
      }
      #pragma unroll
      for (int kk = 0; kk < 4; kk++) A0[kk] = An[kk];
    }
  }
  __syncthreads();

  // ---- phase B0: ALL 8 waves pull this head's V^T fragments into registers
  short8 aV[3];
  #pragma unroll
  for (int kb = 0; kb < 3; kb++) {
    const char* vr = Vt + (w * 16 + cb) * 200;
    short4_t lo = *(const short4_t*)(vr + (kb * 32 + g * 4) * 2);
    short4_t hi = *(const short4_t*)(vr + (kb * 32 + 16 + g * 4) * 2);
    short8 v;
    v[0] = lo[0]; v[1] = lo[1]; v[2] = lo[2]; v[3] = lo[3];
    v[4] = hi[0]; v[5] = hi[1]; v[6] = hi[2]; v[7] = hi[3];
    aV[kb] = v;
  }
  __syncthreads();

  // ---- phase A2: Q projection -> Qd (overwrites dead V^T region) (waves 0..5)
  if (w < 6) {
    short8 A0[4];
    {
      const unsigned short* wb = Wq + (size_t)l * 8;
      #pragma unroll
      for (int kk = 0; kk < 4; kk++) A0[kk] = *(const short8*)(wb + kk * 512);
    }
    #pragma unroll
    for (int nt = 0; nt < 8; nt++) {
      short8 An[4];
      if (nt < 7) {
        const unsigned short* wb = Wq + ((size_t)(nt + 1) * 256 + l) * 8;
        #pragma unroll
        for (int kk = 0; kk < 4; kk++) An[kk] = *(const short8*)(wb + kk * 512);
      }
      f32x4 acc = {0.f, 0.f, 0.f, 0.f};
      #pragma unroll
      for (int kk = 0; kk < 4; kk++)
        acc = __builtin_amdgcn_mfma_f32_16x16x32_bf16(A0[kk], bq[kk], acc, 0, 0, 0);
      float4 bb = *(const float4*)&bq_[nt * 16 + g * 4];
      const int colb = nt * 16 + g * 4;
      short4_t o;
      o[0] = (short)f2bf(acc[0] + bb.x); o[1] = (short)f2bf(acc[1] + bb.y);
      o[2] = (short)f2bf(acc[2] + bb.z); o[3] = (short)f2bf(acc[3] + bb.w);
      *(short4_t*)(Qd + SWZ(row, row * 256 + colb * 2)) = o;
      #pragma unroll
      for (int kk = 0; kk < 4; kk++) A0[kk] = An[kk];
    }
  }
  __syncthreads();

  // ---- phase B: attention, head = wave (8 heads), O overwrites Q region
  {
    const int hb = w * 32;   // byte column offset of this head in Q/K rows
    float bi[6][4];
    #pragma unroll
    for (int kt = 0; kt < 6; kt++)
      #pragma unroll
      for (int r = 0; r < 4; r++)
        bi[kt][r] = bias[kt * 16 + g * 4 + r];

    short8 aK[6];
    #pragma unroll
    for (int kt = 0; kt < 6; kt++) {
      short8 v = {0, 0, 0, 0, 0, 0, 0, 0};
      int key = kt * 16 + cb;
      if (g < 2) v = *(const short8*)(Kd + SWZ(key, key * 256 + hb + g * 16));
      aK[kt] = v;
    }

    #pragma unroll
    for (int qt = 0; qt < 6; qt++) {
      const int qi = qt * 16 + cb;
      short8 aQ = {0, 0, 0, 0, 0, 0, 0, 0};
      if (g < 2) aQ = *(const short8*)(Qd + SWZ(qi, qi * 256 + hb + g * 16));

      f32x4 acc[6];
      #pragma unroll
      for (int kt = 0; kt < 6; kt++) {
        f32x4 z = {0.f, 0.f, 0.f, 0.f};
        acc[kt] = __builtin_amdgcn_mfma_f32_16x16x32_bf16(aK[kt], aQ, z, 0, 0, 0);
      }
      #pragma unroll
      for (int kt = 0; kt < 6; kt++)
        #pragma unroll
        for (int r = 0; r < 4; r++)
          acc[kt][r] = acc[kt][r] * 0.25f + bi[kt][r];
      float mx = -1e30f;
      #pragma unroll
      for (int kt = 0; kt < 6; kt++)
        #pragma unroll
        for (int r = 0; r < 4; r++) mx = fmaxf(mx, acc[kt][r]);
      mx = fmaxf(mx, __shfl_xor(mx, 16));
      mx = fmaxf(mx, __shfl_xor(mx, 32));
      float sm = 0.f;
      #pragma unroll
      for (int kt = 0; kt < 6; kt++)
        #pragma unroll
        for (int r = 0; r < 4; r++) {
          acc[kt][r] = __expf(acc[kt][r] - mx);
          sm += acc[kt][r];
        }
      sm += __shfl_xor(sm, 16);
      sm += __shfl_xor(sm, 32);
      const float inv = 1.f / sm;
      short8 P[3];
      #pragma unroll
      for (int kb = 0; kb < 3; kb++) {
        short8 p;
        #pragma unroll
        for (int e = 0; e < 8; e++) {
          int kt = kb * 2 + (e >> 2);
          p[e] = (short)f2bf(acc[kt][e & 3] * inv);
        }
        P[kb] = p;
      }
      f32x4 accO = {0.f, 0.f, 0.f, 0.f};
      #pragma unroll
      for (int kb = 0; kb < 3; kb++)
        accO = __builtin_amdgcn_mfma_f32_16x16x32_bf16(aV[kb], P[kb], accO, 0, 0, 0);
      if (qi < LS) {
        short4_t o;
        #pragma unroll
        for (int r = 0; r < 4; r++) o[r] = (short)f2bf(accO[r]);
        *(short4_t*)(Qd + SWZ(qi, qi * 256 + hb + g * 8)) = o;
      }
    }
  }
  __syncthreads();

  // ---- phase C: oproj from LDS + residual + LN1 + scatter (waves 0..5), W prefetch
  if (w < 6) {
    const bool ok = row < LS;
    const int t = tok[row];
    short8 bf[4];
    #pragma unroll
    for (int kk = 0; kk < 4; kk++)
      bf[kk] = *(const short8*)(Qd + SWZ(row, row * 256 + kk * 64 + g * 16));

    f32x4 acc[8];
    short8 A0[4];
    {
      const unsigned short* wb = Wo + (size_t)l * 8;
      #pragma unroll
      for (int kk = 0; kk < 4; kk++) A0[kk] = *(const short8*)(wb + kk * 512);
    }
    #pragma unroll
    for (int nt = 0; nt < 8; nt++) {
      short8 An[4];
      if (nt < 7) {
        const unsigned short* wb = Wo + ((size_t)(nt + 1) * 256 + l) * 8;
        #pragma unroll
        for (int kk = 0; kk < 4; kk++) An[kk] = *(const short8*)(wb + kk * 512);
      }
      f32x4 c = {0.f, 0.f, 0.f, 0.f};
      #pragma unroll
      for (int kk = 0; kk < 4; kk++)
        c = __builtin_amdgcn_mfma_f32_16x16x32_bf16(A0[kk], bf[kk], c, 0, 0, 0);
      acc[nt] = c;
      #pragma unroll
      for (int kk = 0; kk < 4; kk++) A0[kk] = An[kk];
    }

    float ta[8][4]; float ssum = 0.f;
    #pragma unroll
    for (int nt = 0; nt < 8; nt++) {
      float4 bo4 = *(const float4*)&bo[nt * 16 + g * 4];
      float4 sv  = *(const float4*)&src[(size_t)t * DM + nt * 16 + g * 4];
      ta[nt][0] = acc[nt][0] + bo4.x + sv.x;
      ta[nt][1] = acc[nt][1] + bo4.y + sv.y;
      ta[nt][2] = acc[nt][2] + bo4.z + sv.z;
      ta[nt][3] = acc[nt][3] + bo4.w + sv.w;
      ssum += ta[nt][0] + ta[nt][1] + ta[nt][2] + ta[nt][3];
    }
    ssum += __shfl_xor(ssum, 16); ssum += __shfl_xor(ssum, 32);
    const float mean = ssum * (1.f / 128.f);
    float vv = 0.f;
    #pragma unroll
    for (int nt = 0; nt < 8; nt++)
      #pragma unroll
      for (int j = 0; j < 4; j++) { float d = ta[nt][j] - mean; vv += d * d; }
    vv += __shfl_xor(vv, 16); vv += __shfl_xor(vv, 32);
    const float rstd = rsqrtf(vv * (1.f / 128.f) + 1e-5f);
    const bool lidar = t < VN;
    const float* gp = lidar ? lg : ig;
    const float* bp = lidar ? lb : ib;
    #pragma unroll
    for (int nt = 0; nt < 8; nt++) {
      float4 g4 = *(const float4*)&gp[nt * 16 + g * 4];
      float4 b4 = *(const float4*)&bp[nt * 16 + g * 4];
      short4_t o;
      o[0] = (short)f2bf((ta[nt][0] - mean) * rstd * g4.x + b4.x);
      o[1] = (short)f2bf((ta[nt][1] - mean) * rstd * g4.y + b4.y);
      o[2] = (short)f2bf((ta[nt][2] - mean) * rstd * g4.z + b4.z);
      o[3] = (short)f2bf((ta[nt][3] - mean) * rstd * g4.w + b4.w);
      if (ok) *(short4_t*)&x1[(size_t)t * DM + nt * 16 + g * 4] = o;
    }
  }
}

// ---------------- K2: fused FFN (swapped MFMA, frag-linear W, barrier-free) ----------------
__global__ __launch_bounds__(256) void k_ffn(
    const unsigned short* __restrict__ x1, const float* __restrict__ src,
    const unsigned short* __restrict__ W1l, const float* __restrict__ B1l,
    const unsigned short* __restrict__ W1i, const float* __restrict__ B1i,
    const unsigned short* __restrict__ W2l, const float* __restrict__ B2l,
    const unsigned short* __restrict__ W2i, const float* __restrict__ B2i,
    const float* __restrict__ lg2, const float* __restrict__ lbb2,
    const float* __restrict__ ig2, const float* __restrict__ ibb2,
    const float* __restrict__ eg, const float* __restrict__ eb,
    float* __restrict__ out)
{
  __shared__ __align__(16) unsigned short hid[64 * 256];
  const int tid = threadIdx.x;
  const int w = tid >> 6, l = tid & 63;
  const int g = l >> 4, cb = l & 15;
  const bool lid = blockIdx.x < NB_L;
  const int t0 = lid ? blockIdx.x * 64 : VN + (blockIdx.x - NB_L) * 64;
  const int limit = lid ? VN : N_TOK;
  const unsigned short* W1 = lid ? W1l : W1i;
  const float* B1 = lid ? B1l : B1i;
  const unsigned short* W2 = lid ? W2l : W2i;
  const float* B2 = lid ? B2l : B2i;
  const float* g2  = lid ? lg2  : ig2;
  const float* bb2 = lid ? lbb2 : ibb2;

  const int row = w * 16 + cb;
  const int t = t0 + row;
  const int tc = (t < limit) ? t : (limit - 1);
  const bool ok = t < limit;

  short8 b1[4];
  #pragma unroll
  for (int kk = 0; kk < 4; kk++)
    b1[kk] = *(const short8*)&x1[(size_t)tc * DM + kk * 32 + g * 8];

  for (int nt = 0; nt < 16; nt++) {
    const unsigned short* wbase = W1 + ((size_t)nt * 256 + l) * 8;
    short8 A[4];
    #pragma unroll
    for (int kk = 0; kk < 4; kk++) A[kk] = *(const short8*)(wbase + kk * 512);
    f32x4 acc = {0.f, 0.f, 0.f, 0.f};
    #pragma unroll
    for (int kk = 0; kk < 4; kk++)
      acc = __builtin_amdgcn_mfma_f32_16x16x32_bf16(A[kk], b1[kk], acc, 0, 0, 0);
    float4 bb = *(const float4*)&B1[nt * 16 + g * 4];
    short4_t h;
    h[0] = (short)f2bf(fmaxf(acc[0] + bb.x, 0.f));
    h[1] = (short)f2bf(fmaxf(acc[1] + bb.y, 0.f));
    h[2] = (short)f2bf(fmaxf(acc[2] + bb.z, 0.f));
    h[3] = (short)f2bf(fmaxf(acc[3] + bb.w, 0.f));
    *(short4_t*)((char*)hid + SWZ(row, row * 512 + nt * 32 + g * 8)) = h;
  }

  short8 b2[8];
  #pragma unroll
  for (int kk = 0; kk < 8; kk++)
    b2[kk] = *(const short8*)((const char*)hid + SWZ(row, row * 512 + kk * 64 + g * 16));

  f32x4 acc2[8];
  for (int nt = 0; nt < 8; nt++) {
    const unsigned short* wbase = W2 + ((size_t)nt * 512 + l) * 8;
    short8 A[8];
    #pragma unroll
    for (int kk = 0; kk < 8; kk++) A[kk] = *(const short8*)(wbase + kk * 512);
    f32x4 c = {0.f, 0.f, 0.f, 0.f};
    #pragma unroll
    for (int kk = 0; kk < 8; kk++)
      c = __builtin_amdgcn_mfma_f32_16x16x32_bf16(A[kk], b2[kk], c, 0, 0, 0);
    acc2[nt] = c;
  }

  float ta[8][4]; float s = 0.f;
  #pragma unroll
  for (int nt = 0; nt < 8; nt++) {
    short4_t xv = *(const short4_t*)&x1[(size_t)tc * DM + nt * 16 + g * 4];
    float4 bb = *(const float4*)&B2[nt * 16 + g * 4];
    ta[nt][0] = bf2f((unsigned short)xv[0]) + acc2[nt][0] + bb.x;
    ta[nt][1] = bf2f((unsigned short)xv[1]) + acc2[nt][1] + bb.y;
    ta[nt][2] = bf2f((unsigned short)xv[2]) + acc2[nt][2] + bb.z;
    ta[nt][3] = bf2f((unsigned short)xv[3]) + acc2[nt][3] + bb.w;
    s += ta[nt][0] + ta[nt][1] + ta[nt][2] + ta[nt][3];
  }
  s += __shfl_xor(s, 16); s += __shfl_xor(s, 32);
  const float mean = s * (1.f / 128.f);
  float vv = 0.f;
  #pragma unroll
  for (int nt = 0; nt < 8; nt++)
    #pragma unroll
    for (int j = 0; j < 4; j++) { float d = ta[nt][j] - mean; vv += d * d; }
  vv += __shfl_xor(vv, 16); vv += __shfl_xor(vv, 32);
  const float rstd = rsqrtf(vv * (1.f / 128.f) + 1e-5f);

  float za[8][4]; float s2 = 0.f;
  #pragma unroll
  for (int nt = 0; nt < 8; nt++) {
    float4 g4 = *(const float4*)&g2[nt * 16 + g * 4];
    float4 b4 = *(const float4*)&bb2[nt * 16 + g * 4];
    float4 sv = *(const float4*)&src[(size_t)tc * DM + nt * 16 + g * 4];
    za[nt][0] = (ta[nt][0] - mean) * rstd * g4.x + b4.x + sv.x;
    za[nt][1] = (ta[nt][1] - mean) * rstd * g4.y + b4.y + sv.y;
    za[nt][2] = (ta[nt][2] - mean) * rstd * g4.z + b4.z + sv.z;
    za[nt][3] = (ta[nt][3] - mean) * rstd * g4.w + b4.w + sv.w;
    s2 += za[nt][0] + za[nt][1] + za[nt][2] + za[nt][3];
  }
  s2 += __shfl_xor(s2, 16); s2 += __shfl_xor(s2, 32);
  const float mean2 = s2 * (1.f / 128.f);
  float vv2 = 0.f;
  #pragma unroll
  for (int nt = 0; nt < 8; nt++)
    #pragma unroll
    for (int j = 0; j < 4; j++) { float d = za[nt][j] - mean2; vv2 += d * d; }
  vv2 += __shfl_xor(vv2, 16); vv2 += __shfl_xor(vv2, 32);
  const float rstd2 = rsqrtf(vv2 * (1.f / 128.f) + 1e-5f);

  #pragma unroll
  for (int nt = 0; nt < 8; nt++) {
    float4 e4 = *(const float4*)&eg[nt * 16 + g * 4];
    float4 eb4 = *(const float4*)&eb[nt * 16 + g * 4];
    float4 o;
    o.x = (za[nt][0] - mean2) * rstd2 * e4.x + eb4.x;
    o.y = (za[nt][1] - mean2) * rstd2 * e4.y + eb4.y;
    o.z = (za[nt][2] - mean2) * rstd2 * e4.z + eb4.z;
    o.w = (za[nt][3] - mean2) * rstd2 * e4.w + eb4.w;
    if (ok) *(float4*)&out[(size_t)t * DM + nt * 16 + g * 4] = o;
  }
}

extern "C" void kernel_launch(void* const* d_in, const int* in_sizes, int n_in,
                              void* d_out, int out_size, void* d_ws, size_t ws_size,
                              hipStream_t stream) {
  (void)in_sizes; (void)n_in; (void)out_size;
  const float* src  = (const float*)d_in[0];
  const float* pos  = (const float*)d_in[1];
  const int*   inds = (const int*)d_in[2];
  const unsigned char* masks = (const unsigned char*)d_in[3];
  const float* Wqkv = (const float*)d_in[5];
  const float* bqkv = (const float*)d_in[6];
  const float* Wo   = (const float*)d_in[7];
  const float* bo   = (const float*)d_in[8];
  const float* lin1_w = (const float*)d_in[9];
  const float* lin1_b = (const float*)d_in[10];
  const float* lin2_w = (const float*)d_in[11];
  const float* lin2_b = (const float*)d_in[12];
  const float* n1_g = (const float*)d_in[13];
  const float* n1_b = (const float*)d_in[14];
  const float* n2_g = (const float*)d_in[15];
  const float* n2_b = (const float*)d_in[16];
  const float* l_lin1_w = (const float*)d_in[17];
  const float* l_lin1_b = (const float*)d_in[18];
  const float* l_lin2_w = (const float*)d_in[19];
  const float* l_lin2_b = (const float*)d_in[20];
  const float* ln1_g = (const float*)d_in[21];
  const float* ln1_b = (const float*)d_in[22];
  const float* ln2_g = (const float*)d_in[23];
  const float* ln2_b = (const float*)d_in[24];
  const float* enc_g = (const float*)d_in[25];
  const float* enc_b = (const float*)d_in[26];

  const size_t buf = (size_t)N_TOK * DM;
  if (ws_size < (buf + 196608) * sizeof(unsigned short)) return;
  unsigned short* x1  = (unsigned short*)d_ws;
  unsigned short* Wbf = x1 + buf;
  unsigned short* WbQKV = Wbf;                 // chunks     0.. 6143
  unsigned short* WbO   = Wbf + 6144  * 8;     // chunks  6144.. 8191
  unsigned short* Wb1L  = Wbf + 8192  * 8;     // chunks  8192..12287
  unsigned short* Wb1I  = Wbf + 12288 * 8;     // chunks 12288..16383
  unsigned short* Wb2L  = Wbf + 16384 * 8;     // chunks 16384..20479
  unsigned short* Wb2I  = Wbf + 20480 * 8;     // chunks 20480..24575

  k_wconv<<<96, 256, 0, stream>>>(Wqkv, Wo, l_lin1_w, lin1_w, l_lin2_w, lin2_w, Wbf);
  k_set<<<NS, 512, 0, stream>>>(src, pos, inds, masks, WbQKV, bqkv, WbO, bo,
                                ln1_g, ln1_b, n1_g, n1_b, x1);
  k_ffn<<<NB_L + NB_I, 256, 0, stream>>>(x1, src,
                                         Wb1L, l_lin1_b, Wb1I, lin1_b,
                                         Wb2L, l_lin2_b, Wb2I, lin2_b,
                                         ln2_g, ln2_b, n2_g, n2_b,
                                         enc_g, enc_b, (float*)d_out);
}

// Round 2
// 133.935 us; speedup vs baseline: 1.3892x; 1.3892x over previous
//
#include <hip/hip_runtime.h>
#include <hip/hip_bf16.h>
#include <cmath>

#define N_TOK 90000
#define DM 128
#define NH 8
#define DH 16
#define NS 1000
#define LS 90
#define LSP 96
#define DFF 256
#define VN 45000
#define NB_L 704   // ceil(VN/64)
#define NB_I 704   // ceil((N_TOK-VN)/64)

typedef __attribute__((ext_vector_type(8))) short short8;
typedef __attribute__((ext_vector_type(4))) short short4_t;
typedef __attribute__((ext_vector_type(4))) float f32x4;

#define SWZ(row, byte) ((byte) ^ (((row) & 7) << 4))

__device__ __forceinline__ unsigned short f2bf(float f) {
  __hip_bfloat16 h = __float2bfloat16(f);
  union { __hip_bfloat16 h; unsigned short u; } c; c.h = h; return c.u;
}
__device__ __forceinline__ float bf2f(unsigned short u) {
  union { unsigned short u; __hip_bfloat16 h; } c; c.u = u; return __bfloat162float(c.h);
}

// ---------------- K0: weights fp32 -> bf16, FRAGMENT-LINEAR layout ----------------
__global__ __launch_bounds__(256) void k_wconv(
    const float* __restrict__ a0, const float* __restrict__ a1,
    const float* __restrict__ a2, const float* __restrict__ a3,
    const float* __restrict__ a4, const float* __restrict__ a5,
    unsigned short* __restrict__ dst)
{
  int c = blockIdx.x * 256 + threadIdx.x;   // 96 blocks * 256 = 24576 chunks
  const float* s; int base, kkn, K;
  if      (c <  6144) { s = a0; base = 0;     kkn = 4; K = 128; }  // Wqkv 384x128
  else if (c <  8192) { s = a1; base = 6144;  kkn = 4; K = 128; }  // Wo   128x128
  else if (c < 12288) { s = a2; base = 8192;  kkn = 4; K = 128; }  // W1l  256x128
  else if (c < 16384) { s = a3; base = 12288; kkn = 4; K = 128; }  // W1i  256x128
  else if (c < 20480) { s = a4; base = 16384; kkn = 8; K = 256; }  // W2l  128x256
  else                { s = a5; base = 20480; kkn = 8; K = 256; }  // W2i  128x256
  int lc = c - base;
  int nt = lc / (kkn * 64);
  int rem = lc - nt * (kkn * 64);
  int kk = rem >> 6, l = rem & 63;
  int row = nt * 16 + (l & 15);
  int col = kk * 32 + (l >> 4) * 8;
  const float* sp = s + (size_t)row * K + col;
  short8 o;
  #pragma unroll
  for (int e = 0; e < 8; e++) o[e] = (short)f2bf(sp[e]);
  *(short8*)&dst[(size_t)c * 8] = o;
}

// ---------------- K1: per-set megakernel, LDS union (V^T then Q) ----------------
// grid NS x 512 (8 waves). LDS 51200 -> 3 blocks/CU possible.
// Register discipline: no An prefetch in A1/A2 (keeps natural pressure <= ~84 so
// HW can schedule 6 waves/EU); carried across barriers: bq[4] (16) + aV[3] (12).
__global__ __launch_bounds__(512, 4) void k_set(
    const float* __restrict__ src, const float* __restrict__ pos,
    const int* __restrict__ inds, const unsigned char* __restrict__ masks,
    const unsigned short* __restrict__ Wq, const float* __restrict__ bq_,
    const unsigned short* __restrict__ Wo, const float* __restrict__ bo,
    const float* __restrict__ lg, const float* __restrict__ lb,
    const float* __restrict__ ig, const float* __restrict__ ib,
    unsigned short* __restrict__ x1)
{
  // K [96][256B bf16 swizzled] | union{ V^T [128][200B] ; Q/O [96][256B swizzled] }
  __shared__ __align__(16) char QKV[LSP * 256 + 128 * 200];
  __shared__ float bias[LSP];
  __shared__ int tok[LSP];
  const int s = blockIdx.x;
  const int tid = threadIdx.x;
  const int w = tid >> 6, l = tid & 63;
  const int g = l >> 4, cb = l & 15;

  if (tid < LSP) {
    tok[tid] = inds[s * LS + ((tid < LS) ? tid : 0)];
    bias[tid] = (tid < LS && !masks[s * LS + tid]) ? 0.f : -1e9f;
  }
  __syncthreads();

  char* Kd = QKV;
  char* Vt = QKV + LSP * 256;   // V^T: row=channel (128), col=key, 200B rows
  char* Qd = QKV + LSP * 256;   // aliases Vt — written only after aV consumed

  const int row = w * 16 + cb;
  short8 bq[4];                 // gathered q = sf+sp, lives through A1 and A2

  // ---- phase A1: gather + K,V projection -> LDS (waves 0..5), single-stage W loads
  if (w < 6) {
    const int t = tok[row];
    short8 bv[4];
    #pragma unroll
    for (int kk = 0; kk < 4; kk++) {
      const float* sp = &src[(size_t)t * DM + kk * 32 + g * 8];
      const float* pp = &pos[(size_t)t * DM + kk * 32 + g * 8];
      float4 s0 = *(const float4*)sp, s1 = *(const float4*)(sp + 4);
      float4 p0 = *(const float4*)pp, p1 = *(const float4*)(pp + 4);
      short8 q, v;
      q[0] = (short)f2bf(s0.x + p0.x); q[1] = (short)f2bf(s0.y + p0.y);
      q[2] = (short)f2bf(s0.z + p0.z); q[3] = (short)f2bf(s0.w + p0.w);
      q[4] = (short)f2bf(s1.x + p1.x); q[5] = (short)f2bf(s1.y + p1.y);
      q[6] = (short)f2bf(s1.z + p1.z); q[7] = (short)f2bf(s1.w + p1.w);
      v[0] = (short)f2bf(s0.x); v[1] = (short)f2bf(s0.y);
      v[2] = (short)f2bf(s0.z); v[3] = (short)f2bf(s0.w);
      v[4] = (short)f2bf(s1.x); v[5] = (short)f2bf(s1.y);
      v[6] = (short)f2bf(s1.z); v[7] = (short)f2bf(s1.w);
      bq[kk] = q; bv[kk] = v;
    }

    // K projection: tiles 8..15 (uses bq)
    #pragma unroll
    for (int nt = 8; nt < 16; nt++) {
      const unsigned short* wb = Wq + ((size_t)nt * 256 + l) * 8;
      short8 A[4];
      #pragma unroll
      for (int kk = 0; kk < 4; kk++) A[kk] = *(const short8*)(wb + kk * 512);
      f32x4 acc = {0.f, 0.f, 0.f, 0.f};
      #pragma unroll
      for (int kk = 0; kk < 4; kk++)
        acc = __builtin_amdgcn_mfma_f32_16x16x32_bf16(A[kk], bq[kk], acc, 0, 0, 0);
      float4 bb = *(const float4*)&bq_[nt * 16 + g * 4];
      const int colb = (nt & 7) * 16 + g * 4;
      short4_t o;
      o[0] = (short)f2bf(acc[0] + bb.x); o[1] = (short)f2bf(acc[1] + bb.y);
      o[2] = (short)f2bf(acc[2] + bb.z); o[3] = (short)f2bf(acc[3] + bb.w);
      *(short4_t*)(Kd + SWZ(row, row * 256 + colb * 2)) = o;
    }

    // V projection: tiles 16..23 (uses bv) -> transposed store into Vt
    #pragma unroll
    for (int nt = 16; nt < 24; nt++) {
      const unsigned short* wb = Wq + ((size_t)nt * 256 + l) * 8;
      short8 A[4];
      #pragma unroll
      for (int kk = 0; kk < 4; kk++) A[kk] = *(const short8*)(wb + kk * 512);
      f32x4 acc = {0.f, 0.f, 0.f, 0.f};
      #pragma unroll
      for (int kk = 0; kk < 4; kk++)
        acc = __builtin_amdgcn_mfma_f32_16x16x32_bf16(A[kk], bv[kk], acc, 0, 0, 0);
      float4 bb = *(const float4*)&bq_[nt * 16 + g * 4];
      float bba[4] = {bb.x, bb.y, bb.z, bb.w};
      #pragma unroll
      for (int j = 0; j < 4; j++) {
        int ch = (nt - 16) * 16 + g * 4 + j;   // channel 0..127
        *(unsigned short*)(Vt + ch * 200 + row * 2) = f2bf(acc[j] + bba[j]);
      }
    }
  }
  __syncthreads();

  // ---- phase B0: ALL 8 waves pull this head's V^T fragments into registers
  short8 aV[3];
  #pragma unroll
  for (int kb = 0; kb < 3; kb++) {
    const char* vr = Vt + (w * 16 + cb) * 200;
    short4_t lo = *(const short4_t*)(vr + (kb * 32 + g * 4) * 2);
    short4_t hi = *(const short4_t*)(vr + (kb * 32 + 16 + g * 4) * 2);
    short8 v;
    v[0] = lo[0]; v[1] = lo[1]; v[2] = lo[2]; v[3] = lo[3];
    v[4] = hi[0]; v[5] = hi[1]; v[6] = hi[2]; v[7] = hi[3];
    aV[kb] = v;
  }
  __syncthreads();

  // ---- phase A2: Q projection -> Qd (overwrites dead V^T region) (waves 0..5)
  if (w < 6) {
    #pragma unroll
    for (int nt = 0; nt < 8; nt++) {
      const unsigned short* wb = Wq + ((size_t)nt * 256 + l) * 8;
      short8 A[4];
      #pragma unroll
      for (int kk = 0; kk < 4; kk++) A[kk] = *(const short8*)(wb + kk * 512);
      f32x4 acc = {0.f, 0.f, 0.f, 0.f};
      #pragma unroll
      for (int kk = 0; kk < 4; kk++)
        acc = __builtin_amdgcn_mfma_f32_16x16x32_bf16(A[kk], bq[kk], acc, 0, 0, 0);
      float4 bb = *(const float4*)&bq_[nt * 16 + g * 4];
      const int colb = nt * 16 + g * 4;
      short4_t o;
      o[0] = (short)f2bf(acc[0] + bb.x); o[1] = (short)f2bf(acc[1] + bb.y);
      o[2] = (short)f2bf(acc[2] + bb.z); o[3] = (short)f2bf(acc[3] + bb.w);
      *(short4_t*)(Qd + SWZ(row, row * 256 + colb * 2)) = o;
    }
  }
  __syncthreads();

  // ---- phase B: attention, head = wave (8 heads), O overwrites Q region
  {
    const int hb = w * 32;   // byte column offset of this head in Q/K rows
    float bi[6][4];
    #pragma unroll
    for (int kt = 0; kt < 6; kt++)
      #pragma unroll
      for (int r = 0; r < 4; r++)
        bi[kt][r] = bias[kt * 16 + g * 4 + r];

    short8 aK[6];
    #pragma unroll
    for (int kt = 0; kt < 6; kt++) {
      short8 v = {0, 0, 0, 0, 0, 0, 0, 0};
      int key = kt * 16 + cb;
      if (g < 2) v = *(const short8*)(Kd + SWZ(key, key * 256 + hb + g * 16));
      aK[kt] = v;
    }

    #pragma unroll
    for (int qt = 0; qt < 6; qt++) {
      const int qi = qt * 16 + cb;
      short8 aQ = {0, 0, 0, 0, 0, 0, 0, 0};
      if (g < 2) aQ = *(const short8*)(Qd + SWZ(qi, qi * 256 + hb + g * 16));

      f32x4 acc[6];
      #pragma unroll
      for (int kt = 0; kt < 6; kt++) {
        f32x4 z = {0.f, 0.f, 0.f, 0.f};
        acc[kt] = __builtin_amdgcn_mfma_f32_16x16x32_bf16(aK[kt], aQ, z, 0, 0, 0);
      }
      #pragma unroll
      for (int kt = 0; kt < 6; kt++)
        #pragma unroll
        for (int r = 0; r < 4; r++)
          acc[kt][r] = acc[kt][r] * 0.25f + bi[kt][r];
      float mx = -1e30f;
      #pragma unroll
      for (int kt = 0; kt < 6; kt++)
        #pragma unroll
        for (int r = 0; r < 4; r++) mx = fmaxf(mx, acc[kt][r]);
      mx = fmaxf(mx, __shfl_xor(mx, 16));
      mx = fmaxf(mx, __shfl_xor(mx, 32));
      float sm = 0.f;
      #pragma unroll
      for (int kt = 0; kt < 6; kt++)
        #pragma unroll
        for (int r = 0; r < 4; r++) {
          acc[kt][r] = __expf(acc[kt][r] - mx);
          sm += acc[kt][r];
        }
      sm += __shfl_xor(sm, 16);
      sm += __shfl_xor(sm, 32);
      const float inv = 1.f / sm;
      short8 P[3];
      #pragma unroll
      for (int kb = 0; kb < 3; kb++) {
        short8 p;
        #pragma unroll
        for (int e = 0; e < 8; e++) {
          int kt = kb * 2 + (e >> 2);
          p[e] = (short)f2bf(acc[kt][e & 3] * inv);
        }
        P[kb] = p;
      }
      f32x4 accO = {0.f, 0.f, 0.f, 0.f};
      #pragma unroll
      for (int kb = 0; kb < 3; kb++)
        accO = __builtin_amdgcn_mfma_f32_16x16x32_bf16(aV[kb], P[kb], accO, 0, 0, 0);
      if (qi < LS) {
        short4_t o;
        #pragma unroll
        for (int r = 0; r < 4; r++) o[r] = (short)f2bf(accO[r]);
        *(short4_t*)(Qd + SWZ(qi, qi * 256 + hb + g * 8)) = o;
      }
    }
  }
  __syncthreads();

  // ---- phase C: oproj from LDS + residual + LN1 + scatter (waves 0..5), W prefetch
  if (w < 6) {
    const bool ok = row < LS;
    const int t = tok[row];
    short8 bf[4];
    #pragma unroll
    for (int kk = 0; kk < 4; kk++)
      bf[kk] = *(const short8*)(Qd + SWZ(row, row * 256 + kk * 64 + g * 16));

    f32x4 acc[8];
    short8 A0[4];
    {
      const unsigned short* wb = Wo + (size_t)l * 8;
      #pragma unroll
      for (int kk = 0; kk < 4; kk++) A0[kk] = *(const short8*)(wb + kk * 512);
    }
    #pragma unroll
    for (int nt = 0; nt < 8; nt++) {
      short8 An[4];
      if (nt < 7) {
        const unsigned short* wb = Wo + ((size_t)(nt + 1) * 256 + l) * 8;
        #pragma unroll
        for (int kk = 0; kk < 4; kk++) An[kk] = *(const short8*)(wb + kk * 512);
      }
      f32x4 c = {0.f, 0.f, 0.f, 0.f};
      #pragma unroll
      for (int kk = 0; kk < 4; kk++)
        c = __builtin_amdgcn_mfma_f32_16x16x32_bf16(A0[kk], bf[kk], c, 0, 0, 0);
      acc[nt] = c;
      #pragma unroll
      for (int kk = 0; kk < 4; kk++) A0[kk] = An[kk];
    }

    float ta[8][4]; float ssum = 0.f;
    #pragma unroll
    for (int nt = 0; nt < 8; nt++) {
      float4 bo4 = *(const float4*)&bo[nt * 16 + g * 4];
      float4 sv  = *(const float4*)&src[(size_t)t * DM + nt * 16 + g * 4];
      ta[nt][0] = acc[nt][0] + bo4.x + sv.x;
      ta[nt][1] = acc[nt][1] + bo4.y + sv.y;
      ta[nt][2] = acc[nt][2] + bo4.z + sv.z;
      ta[nt][3] = acc[nt][3] + bo4.w + sv.w;
      ssum += ta[nt][0] + ta[nt][1] + ta[nt][2] + ta[nt][3];
    }
    ssum += __shfl_xor(ssum, 16); ssum += __shfl_xor(ssum, 32);
    const float mean = ssum * (1.f / 128.f);
    float vv = 0.f;
    #pragma unroll
    for (int nt = 0; nt < 8; nt++)
      #pragma unroll
      for (int j = 0; j < 4; j++) { float d = ta[nt][j] - mean; vv += d * d; }
    vv += __shfl_xor(vv, 16); vv += __shfl_xor(vv, 32);
    const float rstd = rsqrtf(vv * (1.f / 128.f) + 1e-5f);
    const bool lidar = t < VN;
    const float* gp = lidar ? lg : ig;
    const float* bp = lidar ? lb : ib;
    #pragma unroll
    for (int nt = 0; nt < 8; nt++) {
      float4 g4 = *(const float4*)&gp[nt * 16 + g * 4];
      float4 b4 = *(const float4*)&bp[nt * 16 + g * 4];
      short4_t o;
      o[0] = (short)f2bf((ta[nt][0] - mean) * rstd * g4.x + b4.x);
      o[1] = (short)f2bf((ta[nt][1] - mean) * rstd * g4.y + b4.y);
      o[2] = (short)f2bf((ta[nt][2] - mean) * rstd * g4.z + b4.z);
      o[3] = (short)f2bf((ta[nt][3] - mean) * rstd * g4.w + b4.w);
      if (ok) *(short4_t*)&x1[(size_t)t * DM + nt * 16 + g * 4] = o;
    }
  }
}

// ---------------- K2: fused FFN (swapped MFMA, frag-linear W, barrier-free) ----------------
__global__ __launch_bounds__(256) void k_ffn(
    const unsigned short* __restrict__ x1, const float* __restrict__ src,
    const unsigned short* __restrict__ W1l, const float* __restrict__ B1l,
    const unsigned short* __restrict__ W1i, const float* __restrict__ B1i,
    const unsigned short* __restrict__ W2l, const float* __restrict__ B2l,
    const unsigned short* __restrict__ W2i, const float* __restrict__ B2i,
    const float* __restrict__ lg2, const float* __restrict__ lbb2,
    const float* __restrict__ ig2, const float* __restrict__ ibb2,
    const float* __restrict__ eg, const float* __restrict__ eb,
    float* __restrict__ out)
{
  __shared__ __align__(16) unsigned short hid[64 * 256];
  const int tid = threadIdx.x;
  const int w = tid >> 6, l = tid & 63;
  const int g = l >> 4, cb = l & 15;
  const bool lid = blockIdx.x < NB_L;
  const int t0 = lid ? blockIdx.x * 64 : VN + (blockIdx.x - NB_L) * 64;
  const int limit = lid ? VN : N_TOK;
  const unsigned short* W1 = lid ? W1l : W1i;
  const float* B1 = lid ? B1l : B1i;
  const unsigned short* W2 = lid ? W2l : W2i;
  const float* B2 = lid ? B2l : B2i;
  const float* g2  = lid ? lg2  : ig2;
  const float* bb2 = lid ? lbb2 : ibb2;

  const int row = w * 16 + cb;
  const int t = t0 + row;
  const int tc = (t < limit) ? t : (limit - 1);
  const bool ok = t < limit;

  short8 b1[4];
  #pragma unroll
  for (int kk = 0; kk < 4; kk++)
    b1[kk] = *(const short8*)&x1[(size_t)tc * DM + kk * 32 + g * 8];

  for (int nt = 0; nt < 16; nt++) {
    const unsigned short* wbase = W1 + ((size_t)nt * 256 + l) * 8;
    short8 A[4];
    #pragma unroll
    for (int kk = 0; kk < 4; kk++) A[kk] = *(const short8*)(wbase + kk * 512);
    f32x4 acc = {0.f, 0.f, 0.f, 0.f};
    #pragma unroll
    for (int kk = 0; kk < 4; kk++)
      acc = __builtin_amdgcn_mfma_f32_16x16x32_bf16(A[kk], b1[kk], acc, 0, 0, 0);
    float4 bb = *(const float4*)&B1[nt * 16 + g * 4];
    short4_t h;
    h[0] = (short)f2bf(fmaxf(acc[0] + bb.x, 0.f));
    h[1] = (short)f2bf(fmaxf(acc[1] + bb.y, 0.f));
    h[2] = (short)f2bf(fmaxf(acc[2] + bb.z, 0.f));
    h[3] = (short)f2bf(fmaxf(acc[3] + bb.w, 0.f));
    *(short4_t*)((char*)hid + SWZ(row, row * 512 + nt * 32 + g * 8)) = h;
  }

  short8 b2[8];
  #pragma unroll
  for (int kk = 0; kk < 8; kk++)
    b2[kk] = *(const short8*)((const char*)hid + SWZ(row, row * 512 + kk * 64 + g * 16));

  f32x4 acc2[8];
  for (int nt = 0; nt < 8; nt++) {
    const unsigned short* wbase = W2 + ((size_t)nt * 512 + l) * 8;
    short8 A[8];
    #pragma unroll
    for (int kk = 0; kk < 8; kk++) A[kk] = *(const short8*)(wbase + kk * 512);
    f32x4 c = {0.f, 0.f, 0.f, 0.f};
    #pragma unroll
    for (int kk = 0; kk < 8; kk++)
      c = __builtin_amdgcn_mfma_f32_16x16x32_bf16(A[kk], b2[kk], c, 0, 0, 0);
    acc2[nt] = c;
  }

  float ta[8][4]; float s = 0.f;
  #pragma unroll
  for (int nt = 0; nt < 8; nt++) {
    short4_t xv = *(const short4_t*)&x1[(size_t)tc * DM + nt * 16 + g * 4];
    float4 bb = *(const float4*)&B2[nt * 16 + g * 4];
    ta[nt][0] = bf2f((unsigned short)xv[0]) + acc2[nt][0] + bb.x;
    ta[nt][1] = bf2f((unsigned short)xv[1]) + acc2[nt][1] + bb.y;
    ta[nt][2] = bf2f((unsigned short)xv[2]) + acc2[nt][2] + bb.z;
    ta[nt][3] = bf2f((unsigned short)xv[3]) + acc2[nt][3] + bb.w;
    s += ta[nt][0] + ta[nt][1] + ta[nt][2] + ta[nt][3];
  }
  s += __shfl_xor(s, 16); s += __shfl_xor(s, 32);
  const float mean = s * (1.f / 128.f);
  float vv = 0.f;
  #pragma unroll
  for (int nt = 0; nt < 8; nt++)
    #pragma unroll
    for (int j = 0; j < 4; j++) { float d = ta[nt][j] - mean; vv += d * d; }
  vv += __shfl_xor(vv, 16); vv += __shfl_xor(vv, 32);
  const float rstd = rsqrtf(vv * (1.f / 128.f) + 1e-5f);

  float za[8][4]; float s2 = 0.f;
  #pragma unroll
  for (int nt = 0; nt < 8; nt++) {
    float4 g4 = *(const float4*)&g2[nt * 16 + g * 4];
    float4 b4 = *(const float4*)&bb2[nt * 16 + g * 4];
    float4 sv = *(const float4*)&src[(size_t)tc * DM + nt * 16 + g * 4];
    za[nt][0] = (ta[nt][0] - mean) * rstd * g4.x + b4.x + sv.x;
    za[nt][1] = (ta[nt][1] - mean) * rstd * g4.y + b4.y + sv.y;
    za[nt][2] = (ta[nt][2] - mean) * rstd * g4.z + b4.z + sv.z;
    za[nt][3] = (ta[nt][3] - mean) * rstd * g4.w + b4.w + sv.w;
    s2 += za[nt][0] + za[nt][1] + za[nt][2] + za[nt][3];
  }
  s2 += __shfl_xor(s2, 16); s2 += __shfl_xor(s2, 32);
  const float mean2 = s2 * (1.f / 128.f);
  float vv2 = 0.f;
  #pragma unroll
  for (int nt = 0; nt < 8; nt++)
    #pragma unroll
    for (int j = 0; j < 4; j++) { float d = za[nt][j] - mean2; vv2 += d * d; }
  vv2 += __shfl_xor(vv2, 16); vv2 += __shfl_xor(vv2, 32);
  const float rstd2 = rsqrtf(vv2 * (1.f / 128.f) + 1e-5f);

  #pragma unroll
  for (int nt = 0; nt < 8; nt++) {
    float4 e4 = *(const float4*)&eg[nt * 16 + g * 4];
    float4 eb4 = *(const float4*)&eb[nt * 16 + g * 4];
    float4 o;
    o.x = (za[nt][0] - mean2) * rstd2 * e4.x + eb4.x;
    o.y = (za[nt][1] - mean2) * rstd2 * e4.y + eb4.y;
    o.z = (za[nt][2] - mean2) * rstd2 * e4.z + eb4.z;
    o.w = (za[nt][3] - mean2) * rstd2 * e4.w + eb4.w;
    if (ok) *(float4*)&out[(size_t)t * DM + nt * 16 + g * 4] = o;
  }
}

extern "C" void kernel_launch(void* const* d_in, const int* in_sizes, int n_in,
                              void* d_out, int out_size, void* d_ws, size_t ws_size,
                              hipStream_t stream) {
  (void)in_sizes; (void)n_in; (void)out_size;
  const float* src  = (const float*)d_in[0];
  const float* pos  = (const float*)d_in[1];
  const int*   inds = (const int*)d_in[2];
  const unsigned char* masks = (const unsigned char*)d_in[3];
  const float* Wqkv = (const float*)d_in[5];
  const float* bqkv = (const float*)d_in[6];
  const float* Wo   = (const float*)d_in[7];
  const float* bo   = (const float*)d_in[8];
  const float* lin1_w = (const float*)d_in[9];
  const float* lin1_b = (const float*)d_in[10];
  const float* lin2_w = (const float*)d_in[11];
  const float* lin2_b = (const float*)d_in[12];
  const float* n1_g = (const float*)d_in[13];
  const float* n1_b = (const float*)d_in[14];
  const float* n2_g = (const float*)d_in[15];
  const float* n2_b = (const float*)d_in[16];
  const float* l_lin1_w = (const float*)d_in[17];
  const float* l_lin1_b = (const float*)d_in[18];
  const float* l_lin2_w = (const float*)d_in[19];
  const float* l_lin2_b = (const float*)d_in[20];
  const float* ln1_g = (const float*)d_in[21];
  const float* ln1_b = (const float*)d_in[22];
  const float* ln2_g = (const float*)d_in[23];
  const float* ln2_b = (const float*)d_in[24];
  const float* enc_g = (const float*)d_in[25];
  const float* enc_b = (const float*)d_in[26];

  const size_t buf = (size_t)N_TOK * DM;
  if (ws_size < (buf + 196608) * sizeof(unsigned short)) return;
  unsigned short* x1  = (unsigned short*)d_ws;
  unsigned short* Wbf = x1 + buf;
  unsigned short* WbQKV = Wbf;                 // chunks     0.. 6143
  unsigned short* WbO   = Wbf + 6144  * 8;     // chunks  6144.. 8191
  unsigned short* Wb1L  = Wbf + 8192  * 8;     // chunks  8192..12287
  unsigned short* Wb1I  = Wbf + 12288 * 8;     // chunks 12288..16383
  unsigned short* Wb2L  = Wbf + 16384 * 8;     // chunks 16384..20479
  unsigned short* Wb2I  = Wbf + 20480 * 8;     // chunks 20480..24575

  k_wconv<<<96, 256, 0, stream>>>(Wqkv, Wo, l_lin1_w, lin1_w, l_lin2_w, lin2_w, Wbf);
  k_set<<<NS, 512, 0, stream>>>(src, pos, inds, masks, WbQKV, bqkv, WbO, bo,
                                ln1_g, ln1_b, n1_g, n1_b, x1);
  k_ffn<<<NB_L + NB_I, 256, 0, stream>>>(x1, src,
                                         Wb1L, l_lin1_b, Wb1I, lin1_b,
                                         Wb2L, l_lin2_b, Wb2I, lin2_b,
                                         ln2_g, ln2_b, n2_g, n2_b,
                                         enc_g, enc_b, (float*)d_out);
}